// Round 2
// baseline (281.497 us; speedup 1.0000x reference)
//
#include <hip/hip_runtime.h>
#include <math.h>

// Problem constants: NE=1e6, NR=1000, D=32, B=2^20, CURV=1
#define NR_ 1000
#define NE_ 1000000
#define D_ 32
#define HALF_ 16
#define EMB_DIM 33            // fp32 entity row: [x0, spatial(32)]
#define TAB_STRIDE 68         // precomputed relation row (272 B)

// ---------------------------------------------------------------------------
// Kernel 0 (tab prep, tiny): 4 lanes per relation, 1000 relations.
// Row layout (float):
//   [0:16) cos(rot)  [16:32) sin(rot)  [32:64) (sinh(vn)/vn)*0.1*trans
//   (trans part interleaved to match main's lane layout:
//    [32+4q..36+4q) = kt dims 4q..4q+3, [48+4q..52+4q) = kt dims 16+4q..)
//   [64] cosh(rap0) [65] sinh(rap0) [66] cosh(vn) [67] pad
// Lane q of a relation computes cos/sin for rot dims 4q..4q+3 and kt for
// trans dims {4q..4q+3, 16+4q..16+4q+3}; s2 reduced over the 4-lane group.
// ---------------------------------------------------------------------------
__global__ __launch_bounds__(256) void tab_prep_kernel(
    const float* __restrict__ boost_w, const float* __restrict__ rot_w,
    const float* __restrict__ trans_w, float* __restrict__ tab) {
  const int t = blockIdx.x * 256 + threadIdx.x;
  const int r = t >> 2, q = t & 3;
  if (r >= NR_) return;
  const float* ro = rot_w   + (size_t)r * D_ + 4 * q;       // rot dims 4q..
  const float* ta = trans_w + (size_t)r * D_ + 4 * q;       // trans a-dims
  const float* tb = ta + HALF_;                             // trans b-dims
  float* o = tab + (size_t)r * TAB_STRIDE;

  float ta0 = ta[0], ta1 = ta[1], ta2 = ta[2], ta3 = ta[3];
  float tb0 = tb[0], tb1 = tb[1], tb2 = tb[2], tb3 = tb[3];
  float s2 = ta0 * ta0;
  s2 = fmaf(ta1, ta1, s2); s2 = fmaf(ta2, ta2, s2); s2 = fmaf(ta3, ta3, s2);
  s2 = fmaf(tb0, tb0, s2); s2 = fmaf(tb1, tb1, s2);
  s2 = fmaf(tb2, tb2, s2); s2 = fmaf(tb3, tb3, s2);
  s2 += __shfl_xor(s2, 1);
  s2 += __shfl_xor(s2, 2);

  float vn = sqrtf(fmaxf(0.01f * s2, 1e-6f));
  float k  = sinhf(vn) / vn * 0.1f;

  #pragma unroll
  for (int m = 0; m < 4; ++m) {
    float th = ro[m];
    o[4 * q + m]         = cosf(th);   // cos dims 4q+m
    o[HALF_ + 4 * q + m] = sinf(th);   // sin dims 4q+m
  }
  o[32 + 4 * q + 0] = k * ta0; o[32 + 4 * q + 1] = k * ta1;
  o[32 + 4 * q + 2] = k * ta2; o[32 + 4 * q + 3] = k * ta3;
  o[48 + 4 * q + 0] = k * tb0; o[48 + 4 * q + 1] = k * tb1;
  o[48 + 4 * q + 2] = k * tb2; o[48 + 4 * q + 3] = k * tb3;

  if (q == 0) {
    float rap = fminf(fmaxf(boost_w[(size_t)r * D_], -2.f), 2.f);
    o[64] = coshf(rap);
    o[65] = sinhf(rap);
    o[66] = coshf(vn);
    o[67] = 0.f;
  }
}

// ---------------------------------------------------------------------------
// Kernel 1: main scoring — DIRECT fp32 gather, no entity repack, LDS-free.
// Lanes 4e..4e+3 own one output element; lane q covers spatial dims
// {4q..4q+3, 16+4q..16+4q+3} so rotation pairs (j, 16+j) are in-lane.
// Per lane: 8 fp32 head dims + 8 fp32 tail dims + stored x0/t0 (all
// independent scalar loads, issued back-to-back -> deep vmcnt queue).
// Row footprint ~3 cache lines; unique-entity HBM fetch ~166 MB, repeats
// hit Infinity Cache (132 MB table < 256 MB L3). Stored x0/t0 delete the
// hsq/tsq recompute+reduce of the fp16 variant (16 FMA + 4 shfl saved).
// Cross-lane work: 4 __shfl_xor total (n2, dot).
// ---------------------------------------------------------------------------
__global__ __launch_bounds__(256) void lorentz_direct_kernel(
    const int* __restrict__ heads, const int* __restrict__ rels,
    const int* __restrict__ tails, const float* __restrict__ emb,
    const float* __restrict__ bias, const float* __restrict__ tab,
    float* __restrict__ out, int n) {
  const int q = threadIdx.x & 3;                       // dim-chunk in group
  const int e = (blockIdx.x * 256 + threadIdx.x) >> 2; // element id
  const int i = (e < n) ? e : (n - 1);                 // clamp: lanes active

  const int hd = heads[i];
  const int rl = rels[i];
  const int tl = tails[i];

  const float* __restrict__ hrow = emb + (size_t)hd * EMB_DIM;
  const float* __restrict__ trow = emb + (size_t)tl * EMB_DIM;

  // ---- Issue all gathers up front (independent after index loads) ----
  const float hx0 = hrow[0];                    // stored head time component
  const float a0 = hrow[1 + 4 * q], a1 = hrow[2 + 4 * q],
              a2 = hrow[3 + 4 * q], a3 = hrow[4 + 4 * q];
  const float b0 = hrow[17 + 4 * q], b1 = hrow[18 + 4 * q],
              b2 = hrow[19 + 4 * q], b3 = hrow[20 + 4 * q];
  const float tx0 = trow[0];                    // stored tail time component
  const float ta0 = trow[1 + 4 * q], ta1 = trow[2 + 4 * q],
              ta2 = trow[3 + 4 * q], ta3 = trow[4 + 4 * q];
  const float tb0 = trow[17 + 4 * q], tb1 = trow[18 + 4 * q],
              tb2 = trow[19 + 4 * q], tb3 = trow[20 + 4 * q];

  const float4* __restrict__ T =
      reinterpret_cast<const float4*>(tab + (size_t)rl * TAB_STRIDE);
  const float4 cq = T[q];        // cos  dims 4q..4q+3
  const float4 sq = T[4 + q];    // sin  dims 4q..4q+3
  const float4 ka = T[8 + q];    // kt   dims 4q..4q+3
  const float4 kb = T[12 + q];   // kt   dims 16+4q..16+4q+3
  const float4 hp = T[16];       // {cosh(rap), sinh(rap), cosh(vn), pad}
  const float bsum = bias[hd] + bias[tl];

  // ---- Rotation (pairs (j, 16+j) in-lane by dim split) ----
  float rA0 = cq.x * a0 - sq.x * b0;
  float rA1 = cq.y * a1 - sq.y * b1;
  float rA2 = cq.z * a2 - sq.z * b2;
  float rA3 = cq.w * a3 - sq.w * b3;
  const float rB0 = fmaf(sq.x, a0, cq.x * b0);
  const float rB1 = fmaf(sq.y, a1, cq.y * b1);
  const float rB2 = fmaf(sq.z, a2, cq.z * b2);
  const float rB3 = fmaf(sq.w, a3, cq.w * b3);

  // ---- Boost touches spatial dim 0 only (lane q==0); uses stored x0 ----
  if (q == 0) rA0 = fmaf(hx0, hp.y, rA0 * hp.x);
  const float cvn = hp.z;

  // ---- Translation: rs = cvn*r + kt ----
  const float sA0 = fmaf(cvn, rA0, ka.x);
  const float sA1 = fmaf(cvn, rA1, ka.y);
  const float sA2 = fmaf(cvn, rA2, ka.z);
  const float sA3 = fmaf(cvn, rA3, ka.w);
  const float sB0 = fmaf(cvn, rB0, kb.x);
  const float sB1 = fmaf(cvn, rB1, kb.y);
  const float sB2 = fmaf(cvn, rB2, kb.z);
  const float sB3 = fmaf(cvn, rB3, kb.w);

  // ---- n2 (projection) and dot with tail, fused 4-lane reduces ----
  float n2 = sA0 * sA0;
  n2 = fmaf(sA1, sA1, n2); n2 = fmaf(sA2, sA2, n2); n2 = fmaf(sA3, sA3, n2);
  n2 = fmaf(sB0, sB0, n2); n2 = fmaf(sB1, sB1, n2);
  n2 = fmaf(sB2, sB2, n2); n2 = fmaf(sB3, sB3, n2);

  float dot = sA0 * ta0;
  dot = fmaf(sA1, ta1, dot); dot = fmaf(sA2, ta2, dot);
  dot = fmaf(sA3, ta3, dot);
  dot = fmaf(sB0, tb0, dot); dot = fmaf(sB1, tb1, dot);
  dot = fmaf(sB2, tb2, dot); dot = fmaf(sB3, tb3, dot);

  n2  += __shfl_xor(n2, 1);
  dot += __shfl_xor(dot, 1);
  n2  += __shfl_xor(n2, 2);
  dot += __shfl_xor(dot, 2);

  const float ht0 = sqrtf(1.f + n2);
  const float neg_inner = fmaf(ht0, tx0, -dot);  // -lorentz_inner
  const float ic = fmaxf(neg_inner, 1.0f + 1e-6f);
  const float dist = acoshf(ic);
  if (q == 0 && e < n) out[e] = bsum - dist * dist;
}

// ---------------------------------------------------------------------------
// Fallback (ws too small for even the 272 KB tab): fully inline fp32 path.
// ---------------------------------------------------------------------------
__global__ __launch_bounds__(256) void lorentz_fallback_kernel(
    const int* __restrict__ heads, const int* __restrict__ rels,
    const int* __restrict__ tails, const float* __restrict__ emb,
    const float* __restrict__ boost_w, const float* __restrict__ rot_w,
    const float* __restrict__ trans_w, const float* __restrict__ bias,
    float* __restrict__ out, int n) {
  int i = blockIdx.x * blockDim.x + threadIdx.x;
  if (i >= n) return;
  int hd = heads[i], rl = rels[i], tl = tails[i];
  const float* hrow = emb + (size_t)hd * EMB_DIM;
  const float* trow = emb + (size_t)tl * EMB_DIM;
  const float* ro = rot_w   + (size_t)rl * D_;
  const float* tr = trans_w + (size_t)rl * D_;
  float c[HALF_], s[HALF_], kt[D_];
  #pragma unroll
  for (int j = 0; j < HALF_; ++j) { float th = ro[j]; c[j] = cosf(th); s[j] = sinf(th); }
  float s2 = 0.f;
  #pragma unroll
  for (int j = 0; j < D_; ++j) { float v = tr[j]; s2 = fmaf(v, v, s2); }
  float vn = sqrtf(fmaxf(0.01f * s2, 1e-6f));
  float cvn = coshf(vn);
  float k = sinhf(vn) / vn * 0.1f;
  #pragma unroll
  for (int j = 0; j < D_; ++j) kt[j] = k * tr[j];
  float rap = fminf(fmaxf(boost_w[(size_t)rl * D_], -2.f), 2.f);
  float c0 = coshf(rap), s0 = sinhf(rap);
  float x0 = hrow[0];
  float r[D_];
  #pragma unroll
  for (int j = 0; j < HALF_; ++j) {
    float a = hrow[1 + j], b = hrow[1 + HALF_ + j];
    r[j] = c[j] * a - s[j] * b;
    r[HALF_ + j] = s[j] * a + c[j] * b;
  }
  r[0] = fmaf(x0, s0, r[0] * c0);
  float t0 = trow[0], n2 = 0.f, dot = 0.f;
  #pragma unroll
  for (int j = 0; j < D_; ++j) {
    float rsv = fmaf(cvn, r[j], kt[j]);
    n2  = fmaf(rsv, rsv, n2);
    dot = fmaf(rsv, trow[1 + j], dot);
  }
  float ht0 = sqrtf(1.f + n2);
  float neg_inner = fmaf(ht0, t0, -dot);
  float ic = fmaxf(neg_inner, 1.0f + 1e-6f);
  float dist = acoshf(ic);
  out[i] = bias[hd] + bias[tl] - dist * dist;
}

extern "C" void kernel_launch(void* const* d_in, const int* in_sizes, int n_in,
                              void* d_out, int out_size, void* d_ws, size_t ws_size,
                              hipStream_t stream) {
  const int*   heads  = (const int*)d_in[0];
  const int*   rels   = (const int*)d_in[1];
  const int*   tails  = (const int*)d_in[2];
  const float* emb    = (const float*)d_in[3];
  const float* boostw = (const float*)d_in[4];
  const float* rotw   = (const float*)d_in[5];
  const float* transw = (const float*)d_in[6];
  const float* bias   = (const float*)d_in[7];
  float* out = (float*)d_out;
  int n = in_sizes[0];  // B = 1048576

  const size_t tab_bytes = (size_t)NR_ * TAB_STRIDE * sizeof(float);
  dim3 block(256);

  if (ws_size >= tab_bytes) {
    float* tab = (float*)d_ws;
    // 1000 rels * 4 lanes = 4000 threads -> 16 blocks
    tab_prep_kernel<<<dim3((NR_ * 4 + 255) / 256), block, 0, stream>>>(
        boostw, rotw, transw, tab);
    dim3 grid_main((n + 63) / 64);   // 4 lanes per element, 64 elems/block
    lorentz_direct_kernel<<<grid_main, block, 0, stream>>>(
        heads, rels, tails, emb, bias, tab, out, n);
  } else {
    dim3 grid((n + 255) / 256);
    lorentz_fallback_kernel<<<grid, block, 0, stream>>>(
        heads, rels, tails, emb, boostw, rotw, transw, bias, out, n);
  }
}

// Round 3
// 277.500 us; speedup vs baseline: 1.0144x; 1.0144x over previous
//
#include <hip/hip_runtime.h>
#include <hip/hip_fp16.h>
#include <math.h>

// Problem constants: NE=1e6, NR=1000, D=32, B=2^20, CURV=1
#define NR_ 1000
#define NE_ 1000000
#define D_ 32
#define HALF_ 16
#define EMB_DIM 33            // fp32 entity row: [x0, spatial(32)]
#define TAB_STRIDE 68         // precomputed relation row (272 B)
#define H16_BYTES ((size_t)NE_ * 64)   // fp16 table: 16 uints/row, 64 B rows
#define REPACK_BLOCKS 15625   // 15625*256 = 4,000,000 = NE*4 repack threads
#define TAB_BLOCKS 16         // 16*256 = 4096 >= NR*4 lanes

// ---------------------------------------------------------------------------
// Kernel 0 (fused prep).
// Blocks [0, REPACK_BLOCKS): repack entity spatials fp32 -> fp16 into 64 B
// aligned rows, INTERLEAVED chunk layout: 16 B chunk q of row r holds
//   { sp[4q..4q+3], sp[16+4q..16+4q+3] }  as uints {a01,a23,b01,b23}
// so one uint4 per lane pairs rotation dims (j, 16+j) in-lane for the main
// kernel. Plain CACHED loads (R1's nontemporal variant killed line sharing
// across the 8 scalar loads -> multi-fetch of every 64 B line; ~2x read
// amplification). 4 lanes/row: 8 dwords in (coalesced, lines shared within
// the wave), one uint4 out (64 lanes x 16 B = 1 KB contiguous).
// Blocks [REPACK_BLOCKS, +TAB_BLOCKS): per-relation table, 4 lanes/relation:
//   [0:16) cos(rot)  [16:32) sin(rot)
//   [32+4q..36+4q) = kt dims 4q..4q+3, [48+4q..52+4q) = kt dims 16+4q..
//   [64] cosh(rap0) [65] sinh(rap0) [66] cosh(vn) [67] pad
// ---------------------------------------------------------------------------
__global__ __launch_bounds__(256) void prep_kernel(
    const float* __restrict__ emb, const float* __restrict__ boost_w,
    const float* __restrict__ rot_w, const float* __restrict__ trans_w,
    unsigned int* __restrict__ h16, float* __restrict__ tab) {
  const int b = blockIdx.x;
  if (b < REPACK_BLOCKS) {
    int t = b * 256 + threadIdx.x;              // < 4,000,000 exactly
    int r = t >> 2, q = t & 3;
    const float* pa = emb + (size_t)r * EMB_DIM + 1 + 4 * q;  // a-dims 4q..4q+3
    const float* pb = pa + HALF_;                             // b-dims 16+4q..
    float a0 = pa[0], a1 = pa[1], a2 = pa[2], a3 = pa[3];
    float b0 = pb[0], b1 = pb[1], b2 = pb[2], b3 = pb[3];
    union { __half2 h; unsigned int u; } c0, c1, c2, c3;
    c0.h = __half2(__float2half_rn(a0), __float2half_rn(a1));
    c1.h = __half2(__float2half_rn(a2), __float2half_rn(a3));
    c2.h = __half2(__float2half_rn(b0), __float2half_rn(b1));
    c3.h = __half2(__float2half_rn(b2), __float2half_rn(b3));
    uint4 v = make_uint4(c0.u, c1.u, c2.u, c3.u);
    *reinterpret_cast<uint4*>(h16 + (size_t)r * 16 + 4 * q) = v;  // 16B aligned
    return;
  }
  // ---- tab build: 4 lanes per relation ----
  const int t = (b - REPACK_BLOCKS) * 256 + threadIdx.x;
  const int r = t >> 2, q = t & 3;
  if (r >= NR_) return;
  const float* ro = rot_w   + (size_t)r * D_ + 4 * q;       // rot dims 4q..
  const float* ta = trans_w + (size_t)r * D_ + 4 * q;       // trans a-dims
  const float* tb = ta + HALF_;                             // trans b-dims
  float* o = tab + (size_t)r * TAB_STRIDE;

  float ta0 = ta[0], ta1 = ta[1], ta2 = ta[2], ta3 = ta[3];
  float tb0 = tb[0], tb1 = tb[1], tb2 = tb[2], tb3 = tb[3];
  float s2 = ta0 * ta0;
  s2 = fmaf(ta1, ta1, s2); s2 = fmaf(ta2, ta2, s2); s2 = fmaf(ta3, ta3, s2);
  s2 = fmaf(tb0, tb0, s2); s2 = fmaf(tb1, tb1, s2);
  s2 = fmaf(tb2, tb2, s2); s2 = fmaf(tb3, tb3, s2);
  s2 += __shfl_xor(s2, 1);
  s2 += __shfl_xor(s2, 2);

  float vn = sqrtf(fmaxf(0.01f * s2, 1e-6f));
  float k  = sinhf(vn) / vn * 0.1f;

  #pragma unroll
  for (int m = 0; m < 4; ++m) {
    float th = ro[m];
    o[4 * q + m]         = cosf(th);   // cos dims 4q+m
    o[HALF_ + 4 * q + m] = sinf(th);   // sin dims 4q+m
  }
  o[32 + 4 * q + 0] = k * ta0; o[32 + 4 * q + 1] = k * ta1;
  o[32 + 4 * q + 2] = k * ta2; o[32 + 4 * q + 3] = k * ta3;
  o[48 + 4 * q + 0] = k * tb0; o[48 + 4 * q + 1] = k * tb1;
  o[48 + 4 * q + 2] = k * tb2; o[48 + 4 * q + 3] = k * tb3;

  if (q == 0) {
    float rap = fminf(fmaxf(boost_w[(size_t)r * D_], -2.f), 2.f);
    o[64] = coshf(rap);
    o[65] = sinhf(rap);
    o[66] = coshf(vn);
    o[67] = 0.f;
  }
}

// ---------------------------------------------------------------------------
// Kernel 1: main scoring, 4-lane-cooperative, LDS-FREE, fp16 rows.
// Lanes 4e..4e+3 own one output element; lane q covers spatial dims
// {4q..4q+3, 16+4q..16+4q+3} (paired by the interleaved h16 layout, so the
// rotation is in-lane). ONE uint4 gather per lane for head + one for tail:
// 4 consecutive lanes read 4 consecutive 16 B chunks -> one coalesced 64 B
// line per row (vs 192 B/row for the direct fp32 gather; measured 369 MB
// L2-fill at 3.05 TB/s = 122 us in R2 -> predict ~128 MB here). Cross-lane
// work: 8 __shfl_xor (hsq, n2, dot, tsq over the aligned 4-lane group).
// x0/t0 recomputed as sqrt(1+sum(sp^2)) — the reference's own formula.
// ---------------------------------------------------------------------------
__global__ __launch_bounds__(256) void lorentz_coop_kernel(
    const int* __restrict__ heads, const int* __restrict__ rels,
    const int* __restrict__ tails, const unsigned int* __restrict__ h16,
    const float* __restrict__ bias, const float* __restrict__ tab,
    float* __restrict__ out, int n) {
  const int q = threadIdx.x & 3;                      // dim-chunk within group
  const int e = (blockIdx.x * 256 + threadIdx.x) >> 2; // element id
  const int i = (e < n) ? e : (n - 1);                // clamp: lanes stay active

  const int hd = heads[i];
  const int rl = rels[i];
  const int tl = tails[i];

  // ---- Issue both row gathers immediately (independent, 2 outstanding) ----
  const uint4 hv = *reinterpret_cast<const uint4*>(h16 + (size_t)hd * 16 + 4 * q);
  const uint4 tv = *reinterpret_cast<const uint4*>(h16 + (size_t)tl * 16 + 4 * q);

  const float4* __restrict__ T =
      reinterpret_cast<const float4*>(tab + (size_t)rl * TAB_STRIDE);
  const float4 cq = T[q];        // cos  dims 4q..4q+3
  const float4 sq = T[4 + q];    // sin  dims 4q..4q+3
  const float4 ka = T[8 + q];    // kt   dims 4q..4q+3
  const float4 kb = T[12 + q];   // kt   dims 16+4q..16+4q+3
  const float4 hp = T[16];       // {cosh(rap), sinh(rap), cosh(vn), pad}
  const float bsum = bias[hd] + bias[tl];

  // ---- Head unpack: 8 fp16 dims for this lane ----
  union U2 { unsigned int u; __half2 h; };
  U2 u0, u1, u2, u3;
  u0.u = hv.x; u1.u = hv.y; u2.u = hv.z; u3.u = hv.w;
  const float2 fa01 = __half22float2(u0.h);
  const float2 fa23 = __half22float2(u1.h);
  const float2 fb01 = __half22float2(u2.h);
  const float2 fb23 = __half22float2(u3.h);
  const float a0 = fa01.x, a1 = fa01.y, a2 = fa23.x, a3 = fa23.y;
  const float b0 = fb01.x, b1 = fb01.y, b2 = fb23.x, b3 = fb23.y;

  // ---- hsq = sum over all 32 spatial dims (4-lane reduce) ----
  float hsq = a0 * a0;
  hsq = fmaf(a1, a1, hsq); hsq = fmaf(a2, a2, hsq); hsq = fmaf(a3, a3, hsq);
  hsq = fmaf(b0, b0, hsq); hsq = fmaf(b1, b1, hsq);
  hsq = fmaf(b2, b2, hsq); hsq = fmaf(b3, b3, hsq);
  hsq += __shfl_xor(hsq, 1);
  hsq += __shfl_xor(hsq, 2);
  const float x0 = sqrtf(1.f + hsq);          // head time component

  // ---- Rotation (pairs (j, 16+j) are in-lane by construction) ----
  float rA0 = cq.x * a0 - sq.x * b0;
  float rA1 = cq.y * a1 - sq.y * b1;
  float rA2 = cq.z * a2 - sq.z * b2;
  float rA3 = cq.w * a3 - sq.w * b3;
  const float rB0 = fmaf(sq.x, a0, cq.x * b0);
  const float rB1 = fmaf(sq.y, a1, cq.y * b1);
  const float rB2 = fmaf(sq.z, a2, cq.z * b2);
  const float rB3 = fmaf(sq.w, a3, cq.w * b3);

  // ---- Boost touches spatial dim 0 only (lane q==0) ----
  if (q == 0) rA0 = fmaf(x0, hp.y, rA0 * hp.x);
  const float cvn = hp.z;

  // ---- Translation: rs = cvn*r + kt ----
  const float sA0 = fmaf(cvn, rA0, ka.x);
  const float sA1 = fmaf(cvn, rA1, ka.y);
  const float sA2 = fmaf(cvn, rA2, ka.z);
  const float sA3 = fmaf(cvn, rA3, ka.w);
  const float sB0 = fmaf(cvn, rB0, kb.x);
  const float sB1 = fmaf(cvn, rB1, kb.y);
  const float sB2 = fmaf(cvn, rB2, kb.z);
  const float sB3 = fmaf(cvn, rB3, kb.w);

  float n2 = sA0 * sA0;
  n2 = fmaf(sA1, sA1, n2); n2 = fmaf(sA2, sA2, n2); n2 = fmaf(sA3, sA3, n2);
  n2 = fmaf(sB0, sB0, n2); n2 = fmaf(sB1, sB1, n2);
  n2 = fmaf(sB2, sB2, n2); n2 = fmaf(sB3, sB3, n2);
  n2 += __shfl_xor(n2, 1);
  n2 += __shfl_xor(n2, 2);
  const float ht0 = sqrtf(1.f + n2);

  // ---- Tail unpack + dot / tsq (4-lane reduce) ----
  U2 w0, w1, w2, w3;
  w0.u = tv.x; w1.u = tv.y; w2.u = tv.z; w3.u = tv.w;
  const float2 ta01 = __half22float2(w0.h);
  const float2 ta23 = __half22float2(w1.h);
  const float2 tb01 = __half22float2(w2.h);
  const float2 tb23 = __half22float2(w3.h);

  float dot = sA0 * ta01.x;
  dot = fmaf(sA1, ta01.y, dot); dot = fmaf(sA2, ta23.x, dot);
  dot = fmaf(sA3, ta23.y, dot);
  dot = fmaf(sB0, tb01.x, dot); dot = fmaf(sB1, tb01.y, dot);
  dot = fmaf(sB2, tb23.x, dot); dot = fmaf(sB3, tb23.y, dot);

  float tsq = ta01.x * ta01.x;
  tsq = fmaf(ta01.y, ta01.y, tsq); tsq = fmaf(ta23.x, ta23.x, tsq);
  tsq = fmaf(ta23.y, ta23.y, tsq);
  tsq = fmaf(tb01.x, tb01.x, tsq); tsq = fmaf(tb01.y, tb01.y, tsq);
  tsq = fmaf(tb23.x, tb23.x, tsq); tsq = fmaf(tb23.y, tb23.y, tsq);

  dot += __shfl_xor(dot, 1);
  dot += __shfl_xor(dot, 2);
  tsq += __shfl_xor(tsq, 1);
  tsq += __shfl_xor(tsq, 2);
  const float t0 = sqrtf(1.f + tsq);          // tail time component

  const float neg_inner = fmaf(ht0, t0, -dot); // -lorentz_inner
  const float ic = fmaxf(neg_inner, 1.0f + 1e-6f);
  const float dist = acoshf(ic);
  if (q == 0 && e < n) out[e] = bsum - dist * dist;
}

// ---------------------------------------------------------------------------
// Fallback (ws too small): fully inline fp32 scalar path (proven).
// ---------------------------------------------------------------------------
__global__ __launch_bounds__(256) void lorentz_fallback_kernel(
    const int* __restrict__ heads, const int* __restrict__ rels,
    const int* __restrict__ tails, const float* __restrict__ emb,
    const float* __restrict__ boost_w, const float* __restrict__ rot_w,
    const float* __restrict__ trans_w, const float* __restrict__ bias,
    float* __restrict__ out, int n) {
  int i = blockIdx.x * blockDim.x + threadIdx.x;
  if (i >= n) return;
  int hd = heads[i], rl = rels[i], tl = tails[i];
  const float* hrow = emb + (size_t)hd * EMB_DIM;
  const float* trow = emb + (size_t)tl * EMB_DIM;
  const float* ro = rot_w   + (size_t)rl * D_;
  const float* tr = trans_w + (size_t)rl * D_;
  float c[HALF_], s[HALF_], kt[D_];
  #pragma unroll
  for (int j = 0; j < HALF_; ++j) { float th = ro[j]; c[j] = cosf(th); s[j] = sinf(th); }
  float s2 = 0.f;
  #pragma unroll
  for (int j = 0; j < D_; ++j) { float v = tr[j]; s2 = fmaf(v, v, s2); }
  float vn = sqrtf(fmaxf(0.01f * s2, 1e-6f));
  float cvn = coshf(vn);
  float k = sinhf(vn) / vn * 0.1f;
  #pragma unroll
  for (int j = 0; j < D_; ++j) kt[j] = k * tr[j];
  float rap = fminf(fmaxf(boost_w[(size_t)rl * D_], -2.f), 2.f);
  float c0 = coshf(rap), s0 = sinhf(rap);
  float x0 = hrow[0];
  float r[D_];
  #pragma unroll
  for (int j = 0; j < HALF_; ++j) {
    float a = hrow[1 + j], b = hrow[1 + HALF_ + j];
    r[j] = c[j] * a - s[j] * b;
    r[HALF_ + j] = s[j] * a + c[j] * b;
  }
  r[0] = fmaf(x0, s0, r[0] * c0);
  float t0 = trow[0], n2 = 0.f, dot = 0.f;
  #pragma unroll
  for (int j = 0; j < D_; ++j) {
    float rsv = fmaf(cvn, r[j], kt[j]);
    n2  = fmaf(rsv, rsv, n2);
    dot = fmaf(rsv, trow[1 + j], dot);
  }
  float ht0 = sqrtf(1.f + n2);
  float neg_inner = fmaf(ht0, t0, -dot);
  float ic = fmaxf(neg_inner, 1.0f + 1e-6f);
  float dist = acoshf(ic);
  out[i] = bias[hd] + bias[tl] - dist * dist;
}

extern "C" void kernel_launch(void* const* d_in, const int* in_sizes, int n_in,
                              void* d_out, int out_size, void* d_ws, size_t ws_size,
                              hipStream_t stream) {
  const int*   heads  = (const int*)d_in[0];
  const int*   rels   = (const int*)d_in[1];
  const int*   tails  = (const int*)d_in[2];
  const float* emb    = (const float*)d_in[3];
  const float* boostw = (const float*)d_in[4];
  const float* rotw   = (const float*)d_in[5];
  const float* transw = (const float*)d_in[6];
  const float* bias   = (const float*)d_in[7];
  float* out = (float*)d_out;
  int n = in_sizes[0];  // B = 1048576

  const size_t tab_bytes = (size_t)NR_ * TAB_STRIDE * sizeof(float);
  dim3 block(256);

  if (ws_size >= H16_BYTES + tab_bytes) {
    unsigned int* h16 = (unsigned int*)d_ws;
    float* tab = (float*)((char*)d_ws + H16_BYTES);
    prep_kernel<<<dim3(REPACK_BLOCKS + TAB_BLOCKS), block, 0, stream>>>(
        emb, boostw, rotw, transw, h16, tab);
    dim3 grid_main((n + 63) / 64);   // 4 lanes per element, 64 elems/block
    lorentz_coop_kernel<<<grid_main, block, 0, stream>>>(
        heads, rels, tails, h16, bias, tab, out, n);
  } else {
    dim3 grid((n + 255) / 256);
    lorentz_fallback_kernel<<<grid, block, 0, stream>>>(
        heads, rels, tails, emb, boostw, rotw, transw, bias, out, n);
  }
}

// Round 5
// 276.273 us; speedup vs baseline: 1.0189x; 1.0044x over previous
//
#include <hip/hip_runtime.h>
#include <hip/hip_fp16.h>
#include <math.h>

// Problem constants: NE=1e6, NR=1000, D=32, B=2^20, CURV=1
#define NR_ 1000
#define NE_ 1000000
#define D_ 32
#define HALF_ 16
#define EMB_DIM 33            // fp32 entity row: [x0, spatial(32)]
#define TAB_STRIDE 68         // precomputed relation row (272 B)
#define H16_BYTES ((size_t)NE_ * 64)   // fp16 table: 16 uints/row, 64 B rows
#define ROWS_PER_BLOCK 64
#define FLOATS_PER_BLOCK (ROWS_PER_BLOCK * EMB_DIM)   // 2112
#define REPACK_BLOCKS (NE_ / ROWS_PER_BLOCK)          // 15625
#define TAB_BLOCKS 16         // 16*256 = 4096 >= NR*4 lanes

// ---------------------------------------------------------------------------
// Kernel 0 (fused prep), LDS-STAGED STREAMING version.
// Blocks [0, REPACK_BLOCKS): each block owns 64 entity rows = 2112 contiguous
// floats (8448 B). Phase 1: 256 threads read them as 8 fully-coalesced dword
// streams (+ one 64-thread tail stream) into LDS — pure streaming, no row
// stride in the global access pattern (the old 132 B-strided scalar reads
// ran at ~2.5-3 TB/s; this should run near the 6.3 TB/s ceiling).
// Phase 2: thread (r,q) picks its 8 dims from LDS (stride 33 == 1 mod 32 ->
// conflict-free), packs fp16 INTERLEAVED: 16 B chunk q of row r holds
//   { sp[4q..4q+3], sp[16+4q..16+4q+3] }  as uints {a01,a23,b01,b23}
// and writes one uint4 (block writes 4 KB contiguous).
// Blocks [REPACK_BLOCKS, +TAB_BLOCKS): per-relation table, 4 lanes/relation:
//   [0:16) cos(rot)  [16:32) sin(rot)
//   [32+4q..36+4q) = kt dims 4q..4q+3, [48+4q..52+4q) = kt dims 16+4q..
//   [64] cosh(rap0) [65] sinh(rap0) [66] cosh(vn) [67] pad
// ---------------------------------------------------------------------------
__global__ __launch_bounds__(256) void prep_kernel(
    const float* __restrict__ emb, const float* __restrict__ boost_w,
    const float* __restrict__ rot_w, const float* __restrict__ trans_w,
    unsigned int* __restrict__ h16, float* __restrict__ tab) {
  const int b = blockIdx.x;
  if (b < REPACK_BLOCKS) {
    __shared__ float s[FLOATS_PER_BLOCK];
    const int tid = threadIdx.x;
    const float* __restrict__ src = emb + (size_t)b * FLOATS_PER_BLOCK;
    #pragma unroll
    for (int k = 0; k < 8; ++k) s[tid + k * 256] = src[tid + k * 256];
    if (tid < FLOATS_PER_BLOCK - 2048) s[2048 + tid] = src[2048 + tid];
    __syncthreads();

    const int r = tid >> 2, q = tid & 3;                 // row 0..63, chunk
    const float* p = s + r * EMB_DIM + 1 + 4 * q;        // a-dims 4q..4q+3
    float a0 = p[0], a1 = p[1], a2 = p[2], a3 = p[3];
    float b0 = p[HALF_], b1 = p[HALF_ + 1], b2 = p[HALF_ + 2], b3 = p[HALF_ + 3];
    union { __half2 h; unsigned int u; } c0, c1, c2, c3;
    c0.h = __half2(__float2half_rn(a0), __float2half_rn(a1));
    c1.h = __half2(__float2half_rn(a2), __float2half_rn(a3));
    c2.h = __half2(__float2half_rn(b0), __float2half_rn(b1));
    c3.h = __half2(__float2half_rn(b2), __float2half_rn(b3));
    uint4 v = make_uint4(c0.u, c1.u, c2.u, c3.u);
    const size_t row = (size_t)b * ROWS_PER_BLOCK + r;
    *reinterpret_cast<uint4*>(h16 + row * 16 + 4 * q) = v;   // 16B aligned
    return;
  }
  // ---- tab build: 4 lanes per relation ----
  const int t = (b - REPACK_BLOCKS) * 256 + threadIdx.x;
  const int r = t >> 2, q = t & 3;
  if (r >= NR_) return;
  const float* ro = rot_w   + (size_t)r * D_ + 4 * q;       // rot dims 4q..
  const float* ta = trans_w + (size_t)r * D_ + 4 * q;       // trans a-dims
  const float* tb = ta + HALF_;                             // trans b-dims
  float* o = tab + (size_t)r * TAB_STRIDE;

  float ta0 = ta[0], ta1 = ta[1], ta2 = ta[2], ta3 = ta[3];
  float tb0 = tb[0], tb1 = tb[1], tb2 = tb[2], tb3 = tb[3];
  float s2 = ta0 * ta0;
  s2 = fmaf(ta1, ta1, s2); s2 = fmaf(ta2, ta2, s2); s2 = fmaf(ta3, ta3, s2);
  s2 = fmaf(tb0, tb0, s2); s2 = fmaf(tb1, tb1, s2);
  s2 = fmaf(tb2, tb2, s2); s2 = fmaf(tb3, tb3, s2);
  s2 += __shfl_xor(s2, 1);
  s2 += __shfl_xor(s2, 2);

  float vn = sqrtf(fmaxf(0.01f * s2, 1e-6f));
  float k  = sinhf(vn) / vn * 0.1f;

  #pragma unroll
  for (int m = 0; m < 4; ++m) {
    float th = ro[m];
    o[4 * q + m]         = cosf(th);   // cos dims 4q+m
    o[HALF_ + 4 * q + m] = sinf(th);   // sin dims 4q+m
  }
  o[32 + 4 * q + 0] = k * ta0; o[32 + 4 * q + 1] = k * ta1;
  o[32 + 4 * q + 2] = k * ta2; o[32 + 4 * q + 3] = k * ta3;
  o[48 + 4 * q + 0] = k * tb0; o[48 + 4 * q + 1] = k * tb1;
  o[48 + 4 * q + 2] = k * tb2; o[48 + 4 * q + 3] = k * tb3;

  if (q == 0) {
    float rap = fminf(fmaxf(boost_w[(size_t)r * D_], -2.f), 2.f);
    o[64] = coshf(rap);
    o[65] = sinhf(rap);
    o[66] = coshf(vn);
    o[67] = 0.f;
  }
}

// ---------------------------------------------------------------------------
// Kernel 1: main scoring, 4-lane-cooperative, LDS-FREE, fp16 rows.
// Lanes 4e..4e+3 own one output element; lane q covers spatial dims
// {4q..4q+3, 16+4q..16+4q+3} (paired by the interleaved h16 layout, so the
// rotation is in-lane). ONE uint4 gather per lane for head + one for tail:
// 4 consecutive lanes read 4 consecutive 16 B chunks -> one coalesced 64 B
// line per row. Gather floor: 2M x 64 B = 128 MB at ~3 TB/s random rate
// (measured R2) ~= 43 us. Cross-lane work: 8 __shfl_xor.
// x0/t0 recomputed as sqrt(1+sum(sp^2)) — the reference's own formula.
// ---------------------------------------------------------------------------
__global__ __launch_bounds__(256) void lorentz_coop_kernel(
    const int* __restrict__ heads, const int* __restrict__ rels,
    const int* __restrict__ tails, const unsigned int* __restrict__ h16,
    const float* __restrict__ bias, const float* __restrict__ tab,
    float* __restrict__ out, int n) {
  const int q = threadIdx.x & 3;                      // dim-chunk within group
  const int e = (blockIdx.x * 256 + threadIdx.x) >> 2; // element id
  const int i = (e < n) ? e : (n - 1);                // clamp: lanes stay active

  const int hd = heads[i];
  const int rl = rels[i];
  const int tl = tails[i];

  // ---- Issue both row gathers immediately (independent, 2 outstanding) ----
  const uint4 hv = *reinterpret_cast<const uint4*>(h16 + (size_t)hd * 16 + 4 * q);
  const uint4 tv = *reinterpret_cast<const uint4*>(h16 + (size_t)tl * 16 + 4 * q);

  const float4* __restrict__ T =
      reinterpret_cast<const float4*>(tab + (size_t)rl * TAB_STRIDE);
  const float4 cq = T[q];        // cos  dims 4q..4q+3
  const float4 sq = T[4 + q];    // sin  dims 4q..4q+3
  const float4 ka = T[8 + q];    // kt   dims 4q..4q+3
  const float4 kb = T[12 + q];   // kt   dims 16+4q..16+4q+3
  const float4 hp = T[16];       // {cosh(rap), sinh(rap), cosh(vn), pad}
  const float bsum = bias[hd] + bias[tl];

  // ---- Head unpack: 8 fp16 dims for this lane ----
  union U2 { unsigned int u; __half2 h; };
  U2 u0, u1, u2, u3;
  u0.u = hv.x; u1.u = hv.y; u2.u = hv.z; u3.u = hv.w;
  const float2 fa01 = __half22float2(u0.h);
  const float2 fa23 = __half22float2(u1.h);
  const float2 fb01 = __half22float2(u2.h);
  const float2 fb23 = __half22float2(u3.h);
  const float a0 = fa01.x, a1 = fa01.y, a2 = fa23.x, a3 = fa23.y;
  const float b0 = fb01.x, b1 = fb01.y, b2 = fb23.x, b3 = fb23.y;

  // ---- hsq = sum over all 32 spatial dims (4-lane reduce) ----
  float hsq = a0 * a0;
  hsq = fmaf(a1, a1, hsq); hsq = fmaf(a2, a2, hsq); hsq = fmaf(a3, a3, hsq);
  hsq = fmaf(b0, b0, hsq); hsq = fmaf(b1, b1, hsq);
  hsq = fmaf(b2, b2, hsq); hsq = fmaf(b3, b3, hsq);
  hsq += __shfl_xor(hsq, 1);
  hsq += __shfl_xor(hsq, 2);
  const float x0 = sqrtf(1.f + hsq);          // head time component

  // ---- Rotation (pairs (j, 16+j) are in-lane by construction) ----
  float rA0 = cq.x * a0 - sq.x * b0;
  float rA1 = cq.y * a1 - sq.y * b1;
  float rA2 = cq.z * a2 - sq.z * b2;
  float rA3 = cq.w * a3 - sq.w * b3;
  const float rB0 = fmaf(sq.x, a0, cq.x * b0);
  const float rB1 = fmaf(sq.y, a1, cq.y * b1);
  const float rB2 = fmaf(sq.z, a2, cq.z * b2);
  const float rB3 = fmaf(sq.w, a3, cq.w * b3);

  // ---- Boost touches spatial dim 0 only (lane q==0) ----
  if (q == 0) rA0 = fmaf(x0, hp.y, rA0 * hp.x);
  const float cvn = hp.z;

  // ---- Translation: rs = cvn*r + kt ----
  const float sA0 = fmaf(cvn, rA0, ka.x);
  const float sA1 = fmaf(cvn, rA1, ka.y);
  const float sA2 = fmaf(cvn, rA2, ka.z);
  const float sA3 = fmaf(cvn, rA3, ka.w);
  const float sB0 = fmaf(cvn, rB0, kb.x);
  const float sB1 = fmaf(cvn, rB1, kb.y);
  const float sB2 = fmaf(cvn, rB2, kb.z);
  const float sB3 = fmaf(cvn, rB3, kb.w);

  float n2 = sA0 * sA0;
  n2 = fmaf(sA1, sA1, n2); n2 = fmaf(sA2, sA2, n2); n2 = fmaf(sA3, sA3, n2);
  n2 = fmaf(sB0, sB0, n2); n2 = fmaf(sB1, sB1, n2);
  n2 = fmaf(sB2, sB2, n2); n2 = fmaf(sB3, sB3, n2);
  n2 += __shfl_xor(n2, 1);
  n2 += __shfl_xor(n2, 2);
  const float ht0 = sqrtf(1.f + n2);

  // ---- Tail unpack + dot / tsq (4-lane reduce) ----
  U2 w0, w1, w2, w3;
  w0.u = tv.x; w1.u = tv.y; w2.u = tv.z; w3.u = tv.w;
  const float2 ta01 = __half22float2(w0.h);
  const float2 ta23 = __half22float2(w1.h);
  const float2 tb01 = __half22float2(w2.h);
  const float2 tb23 = __half22float2(w3.h);

  float dot = sA0 * ta01.x;
  dot = fmaf(sA1, ta01.y, dot); dot = fmaf(sA2, ta23.x, dot);
  dot = fmaf(sA3, ta23.y, dot);
  dot = fmaf(sB0, tb01.x, dot); dot = fmaf(sB1, tb01.y, dot);
  dot = fmaf(sB2, tb23.x, dot); dot = fmaf(sB3, tb23.y, dot);

  float tsq = ta01.x * ta01.x;
  tsq = fmaf(ta01.y, ta01.y, tsq); tsq = fmaf(ta23.x, ta23.x, tsq);
  tsq = fmaf(ta23.y, ta23.y, tsq);
  tsq = fmaf(tb01.x, tb01.x, tsq); tsq = fmaf(tb01.y, tb01.y, tsq);
  tsq = fmaf(tb23.x, tb23.x, tsq); tsq = fmaf(tb23.y, tb23.y, tsq);

  dot += __shfl_xor(dot, 1);
  dot += __shfl_xor(dot, 2);
  tsq += __shfl_xor(tsq, 1);
  tsq += __shfl_xor(tsq, 2);
  const float t0 = sqrtf(1.f + tsq);          // tail time component

  const float neg_inner = fmaf(ht0, t0, -dot); // -lorentz_inner
  const float ic = fmaxf(neg_inner, 1.0f + 1e-6f);
  const float dist = acoshf(ic);
  if (q == 0 && e < n) out[e] = bsum - dist * dist;
}

// ---------------------------------------------------------------------------
// Fallback (ws too small): fully inline fp32 scalar path (proven).
// ---------------------------------------------------------------------------
__global__ __launch_bounds__(256) void lorentz_fallback_kernel(
    const int* __restrict__ heads, const int* __restrict__ rels,
    const int* __restrict__ tails, const float* __restrict__ emb,
    const float* __restrict__ boost_w, const float* __restrict__ rot_w,
    const float* __restrict__ trans_w, const float* __restrict__ bias,
    float* __restrict__ out, int n) {
  int i = blockIdx.x * blockDim.x + threadIdx.x;
  if (i >= n) return;
  int hd = heads[i], rl = rels[i], tl = tails[i];
  const float* hrow = emb + (size_t)hd * EMB_DIM;
  const float* trow = emb + (size_t)tl * EMB_DIM;
  const float* ro = rot_w   + (size_t)rl * D_;
  const float* tr = trans_w + (size_t)rl * D_;
  float c[HALF_], s[HALF_], kt[D_];
  #pragma unroll
  for (int j = 0; j < HALF_; ++j) { float th = ro[j]; c[j] = cosf(th); s[j] = sinf(th); }
  float s2 = 0.f;
  #pragma unroll
  for (int j = 0; j < D_; ++j) { float v = tr[j]; s2 = fmaf(v, v, s2); }
  float vn = sqrtf(fmaxf(0.01f * s2, 1e-6f));
  float cvn = coshf(vn);
  float k = sinhf(vn) / vn * 0.1f;
  #pragma unroll
  for (int j = 0; j < D_; ++j) kt[j] = k * tr[j];
  float rap = fminf(fmaxf(boost_w[(size_t)rl * D_], -2.f), 2.f);
  float c0 = coshf(rap), s0 = sinhf(rap);
  float x0 = hrow[0];
  float r[D_];
  #pragma unroll
  for (int j = 0; j < HALF_; ++j) {
    float a = hrow[1 + j], b = hrow[1 + HALF_ + j];
    r[j] = c[j] * a - s[j] * b;
    r[HALF_ + j] = s[j] * a + c[j] * b;
  }
  r[0] = fmaf(x0, s0, r[0] * c0);
  float t0 = trow[0], n2 = 0.f, dot = 0.f;
  #pragma unroll
  for (int j = 0; j < D_; ++j) {
    float rsv = fmaf(cvn, r[j], kt[j]);
    n2  = fmaf(rsv, rsv, n2);
    dot = fmaf(rsv, trow[1 + j], dot);
  }
  float ht0 = sqrtf(1.f + n2);
  float neg_inner = fmaf(ht0, t0, -dot);
  float ic = fmaxf(neg_inner, 1.0f + 1e-6f);
  float dist = acoshf(ic);
  out[i] = bias[hd] + bias[tl] - dist * dist;
}

extern "C" void kernel_launch(void* const* d_in, const int* in_sizes, int n_in,
                              void* d_out, int out_size, void* d_ws, size_t ws_size,
                              hipStream_t stream) {
  const int*   heads  = (const int*)d_in[0];
  const int*   rels   = (const int*)d_in[1];
  const int*   tails  = (const int*)d_in[2];
  const float* emb    = (const float*)d_in[3];
  const float* boostw = (const float*)d_in[4];
  const float* rotw   = (const float*)d_in[5];
  const float* transw = (const float*)d_in[6];
  const float* bias   = (const float*)d_in[7];
  float* out = (float*)d_out;
  int n = in_sizes[0];  // B = 1048576

  const size_t tab_bytes = (size_t)NR_ * TAB_STRIDE * sizeof(float);
  dim3 block(256);

  if (ws_size >= H16_BYTES + tab_bytes) {
    unsigned int* h16 = (unsigned int*)d_ws;
    float* tab = (float*)((char*)d_ws + H16_BYTES);
    prep_kernel<<<dim3(REPACK_BLOCKS + TAB_BLOCKS), block, 0, stream>>>(
        emb, boostw, rotw, transw, h16, tab);
    dim3 grid_main((n + 63) / 64);   // 4 lanes per element, 64 elems/block
    lorentz_coop_kernel<<<grid_main, block, 0, stream>>>(
        heads, rels, tails, h16, bias, tab, out, n);
  } else {
    dim3 grid((n + 255) / 256);
    lorentz_fallback_kernel<<<grid, block, 0, stream>>>(
        heads, rels, tails, emb, boostw, rotw, transw, bias, out, n);
  }
}